// Round 2
// baseline (361.877 us; speedup 1.0000x reference)
//
#include <hip/hip_runtime.h>
#include <stdint.h>

// Problem: B=16, S=2048, I=1024, H=1024 (all fp32 in/out)
// out[b,s,h] = tanh( x[b,s,:]·W_ih[h,:] + b_ih[h] + hx[b,:]·W_hh[h,:] + b_hh[h] )
// GEMM: M = B*S = 32768, N = H = 1024, K = I = 1024.
// Round-2 structure: single fused GEMM reads X fp32 directly (inline bf16
// convert into LDS); tiny prep kernel makes W_bf16 + h_term.

#define M_TOT 32768
#define N_TOT 1024
#define K_TOT 1024

typedef short short8 __attribute__((ext_vector_type(8)));   // 8 bf16 (4 VGPRs)
typedef float f32x4  __attribute__((ext_vector_type(4)));   // 4 fp32 acc

// ---- workspace layout (bytes) ----
// [0, 2097152)        W_bf   : 1048576 bf16
// [2097152, 2162688)  h_term : 16384 fp32
#define WS_WBF_OFF 0
#define WS_HT_OFF  2097152

__device__ __forceinline__ unsigned int pack2_bf16_rne(float lo, float hi) {
    unsigned int a = __float_as_uint(lo);
    unsigned int b = __float_as_uint(hi);
    a = (a + 0x7fffu + ((a >> 16) & 1u)) >> 16;          // bf16(lo) in low16
    b = (b + 0x7fffu + ((b >> 16) & 1u)) & 0xffff0000u;  // bf16(hi) in high16
    return a | b;
}

__device__ __forceinline__ float fast_tanh(float z) {
    float e = __expf(2.0f * z);       // v_exp_f32; saturates correctly
    return 1.0f - 2.0f / (e + 1.0f);
}

// ---------------- prep: h_term (blocks 0..4095) + W_ih convert (blocks 4096..4607) -----
__global__ void prep_kernel(const float* __restrict__ hx,
                            const float* __restrict__ whh,
                            const float* __restrict__ bih,
                            const float* __restrict__ bhh,
                            const float* __restrict__ wih,
                            unsigned short* __restrict__ wbf,
                            float* __restrict__ ht) {
    int bid = blockIdx.x;
    if (bid < 4096) {
        // h_term[b,h] = hx[b,:]·W_hh[h,:] + b_ih[h] + b_hh[h]; one wave per (b,h)
        int lane = threadIdx.x & 63;
        int w    = threadIdx.x >> 6;
        int wg   = bid * 4 + w;                 // 0..16383
        int b = wg >> 10, h = wg & 1023;
        const float* hr = hx  + (long long)b * 1024;
        const float* wr = whh + (long long)h * 1024;
        float s = 0.f;
#pragma unroll
        for (int p = 0; p < 4; ++p) {
            int idx = p * 256 + lane * 4;
            float4 a = *(const float4*)(hr + idx);
            float4 c = *(const float4*)(wr + idx);
            s += a.x * c.x + a.y * c.y + a.z * c.z + a.w * c.w;
        }
#pragma unroll
        for (int d = 32; d > 0; d >>= 1) s += __shfl_down(s, d, 64);
        if (lane == 0) ht[wg] = s + bih[h] + bhh[h];
    } else {
        // W_ih fp32 -> bf16: 512 blocks x 256 threads x 8 elements = 1,048,576
        long long base = ((long long)(bid - 4096) * 256 + threadIdx.x) * 8;
        float4 a = *(const float4*)(wih + base);
        float4 b = *(const float4*)(wih + base + 4);
        uint4 o;
        o.x = pack2_bf16_rne(a.x, a.y);
        o.y = pack2_bf16_rne(a.z, a.w);
        o.z = pack2_bf16_rne(b.x, b.y);
        o.w = pack2_bf16_rne(b.z, b.w);
        *(uint4*)(wbf + base) = o;
    }
}

// ---------------- fused GEMM + tanh ----------------
// 128x128 tile, BK=32, 256 threads = 4 waves (2x2), each wave 64x64 via 4x4
// MFMA 16x16x32 bf16. A (X fp32) staged via register convert + ds_write_b128;
// B (W_bf) staged via global_load_lds width=16. XOR chunk swizzle on both LDS
// tiles: slot = (q + (row>>1)) & 3 -> ds_read_b128 only 2-way bank aliased.
#define GLDS16(gp, lp) \
    __builtin_amdgcn_global_load_lds((const __attribute__((address_space(1))) void*)(gp), \
                                     (__attribute__((address_space(3))) void*)(lp), 16, 0, 0)

__global__ __launch_bounds__(256) void gemm_tanh_kernel(
    const float* __restrict__ X,            // [32768,1024] fp32
    const unsigned short* __restrict__ Bm,  // [1024,1024] bf16 (row n K-contiguous)
    const float* __restrict__ ht,           // [16,1024]
    float* __restrict__ out)                // [32768,1024] fp32
{
    __shared__ __align__(16) char lds[16384];   // A: [0,8192), B: [8192,16384)

    const int tid = threadIdx.x;
    const int w = tid >> 6, l = tid & 63;

    // XCD-aware mapping: bid = x + 8*n + 64*g  (x: XCD if round-robin holds,
    // n: tile_n, g: group). The 8 blocks sharing tile_m are consecutive on one
    // XCD -> A row-tile fetched ~once per XCD L2.
    const int bid = blockIdx.x;
    const int x = bid & 7;
    const int tile_n = (bid >> 3) & 7;
    const int g = bid >> 6;                 // 0..31
    const int tile_m = x * 32 + g;          // 0..255
    const int m0 = tile_m << 7, n0 = tile_n << 7;

    // ---- B staging (global_load_lds): wave w instr j covers rows [(w*2+j)*16,+16) ----
    const int r0 = (w * 2 + 0) * 16 + (l >> 2);
    const int r1 = (w * 2 + 1) * 16 + (l >> 2);
    const int slot = l & 3;
    const int qg0 = (slot - (r0 >> 1)) & 3;
    const int qg1 = (slot - (r1 >> 1)) & 3;
    const unsigned short* gB0 = Bm + (long long)(n0 + r0) * K_TOT + qg0 * 8;
    const unsigned short* gB1 = Bm + (long long)(n0 + r1) * K_TOT + qg1 * 8;
    char* ldsB0 = lds + 8192 + (w * 2 + 0) * 1024;
    char* ldsB1 = lds + 8192 + (w * 2 + 1) * 1024;

    // ---- A staging (fp32 -> bf16 in registers -> ds_write_b128) ----
    // 512 chunks (128 rows x 4 slots); thread t handles chunks t and t+256.
    const int rowA0 = tid >> 2;             // 0..63
    const int rowA1 = rowA0 + 64;           // 64..127
    const int sA = tid & 3;
    const int qgA0 = (sA - (rowA0 >> 1)) & 3;
    const int qgA1 = (sA - (rowA1 >> 1)) & 3;
    const float* gAf0 = X + (long long)(m0 + rowA0) * K_TOT + qgA0 * 8;
    const float* gAf1 = X + (long long)(m0 + rowA1) * K_TOT + qgA1 * 8;
    const int ldsAoff0 = rowA0 * 64 + sA * 16;
    const int ldsAoff1 = rowA1 * 64 + sA * 16;

    // ---- fragment read offsets ----
    const int wm = w & 1, wn = w >> 1;
    const int lm = l & 15, q = l >> 4;
    int offA[4], offB[4];
#pragma unroll
    for (int t = 0; t < 4; ++t) {
        int rr = wm * 64 + t * 16 + lm;
        offA[t] = rr * 64 + (((q + (rr >> 1)) & 3) << 4);
        int nn = wn * 64 + t * 16 + lm;
        offB[t] = 8192 + nn * 64 + (((q + (nn >> 1)) & 3) << 4);
    }

    f32x4 acc[4][4];
#pragma unroll
    for (int i = 0; i < 4; ++i)
#pragma unroll
        for (int j = 0; j < 4; ++j)
            acc[i][j] = (f32x4){0.f, 0.f, 0.f, 0.f};

    for (int k0 = 0; k0 < K_TOT; k0 += 32) {
        GLDS16(gB0 + k0, ldsB0);
        GLDS16(gB1 + k0, ldsB1);
        float4 a00 = *(const float4*)(gAf0 + k0);
        float4 a01 = *(const float4*)(gAf0 + k0 + 4);
        float4 a10 = *(const float4*)(gAf1 + k0);
        float4 a11 = *(const float4*)(gAf1 + k0 + 4);
        uint4 w0, w1;
        w0.x = pack2_bf16_rne(a00.x, a00.y);
        w0.y = pack2_bf16_rne(a00.z, a00.w);
        w0.z = pack2_bf16_rne(a01.x, a01.y);
        w0.w = pack2_bf16_rne(a01.z, a01.w);
        w1.x = pack2_bf16_rne(a10.x, a10.y);
        w1.y = pack2_bf16_rne(a10.z, a10.w);
        w1.z = pack2_bf16_rne(a11.x, a11.y);
        w1.w = pack2_bf16_rne(a11.z, a11.w);
        *(uint4*)(lds + ldsAoff0) = w0;
        *(uint4*)(lds + ldsAoff1) = w1;
        __syncthreads();

        short8 af[4], bf[4];
#pragma unroll
        for (int t = 0; t < 4; ++t) {
            af[t] = *(const short8*)(lds + offA[t]);
            bf[t] = *(const short8*)(lds + offB[t]);
        }
#pragma unroll
        for (int mt = 0; mt < 4; ++mt)
#pragma unroll
            for (int nt = 0; nt < 4; ++nt)
                acc[mt][nt] = __builtin_amdgcn_mfma_f32_16x16x32_bf16(
                    af[mt], bf[nt], acc[mt][nt], 0, 0, 0);
        __syncthreads();
    }

    // ---- epilogue: out = tanh(acc + h_term[b, n]) ----
    // C/D layout: col = lane&15 (n), row = (lane>>4)*4 + reg (m)
    const int b = tile_m >> 4;
    float htv[4];
#pragma unroll
    for (int nt = 0; nt < 4; ++nt)
        htv[nt] = ht[b * 1024 + n0 + wn * 64 + nt * 16 + lm];

#pragma unroll
    for (int mt = 0; mt < 4; ++mt) {
#pragma unroll
        for (int nt = 0; nt < 4; ++nt) {
            int n = n0 + wn * 64 + nt * 16 + lm;
#pragma unroll
            for (int r = 0; r < 4; ++r) {
                int m = m0 + wm * 64 + mt * 16 + q * 4 + r;
                float z = acc[mt][nt][r] + htv[nt];
                out[(long long)m * N_TOT + n] = fast_tanh(z);
            }
        }
    }
}

extern "C" void kernel_launch(void* const* d_in, const int* in_sizes, int n_in,
                              void* d_out, int out_size, void* d_ws, size_t ws_size,
                              hipStream_t stream) {
    const float* x    = (const float*)d_in[0];   // [16,2048,1024]
    const float* hx   = (const float*)d_in[1];   // [16,1024]
    const float* wih  = (const float*)d_in[2];   // [1024,1024]
    const float* whh  = (const float*)d_in[3];   // [1024,1024]
    const float* bih  = (const float*)d_in[4];   // [1024]
    const float* bhh  = (const float*)d_in[5];   // [1024]
    float* out = (float*)d_out;

    unsigned short* wbf = (unsigned short*)((char*)d_ws + WS_WBF_OFF);
    float*          htp = (float*)((char*)d_ws + WS_HT_OFF);

    // prep: h_term (4096 blocks) + W convert (512 blocks)
    prep_kernel<<<4608, 256, 0, stream>>>(hx, whh, bih, bhh, wih, wbf, htp);
    // fused GEMM + tanh: 256 m-tiles x 8 n-tiles, XCD-swizzled
    gemm_tanh_kernel<<<2048, 256, 0, stream>>>(x, wbf, htp, out);
}